// Round 4
// baseline (252.769 us; speedup 1.0000x reference)
//
#include <hip/hip_runtime.h>
#include <hip/hip_bf16.h>
#include <stdint.h>

typedef __bf16 bf16x8 __attribute__((ext_vector_type(8)));
typedef float  f32x4  __attribute__((ext_vector_type(4)));

constexpr int Bb = 4;      // batch
constexpr int Tt = 1024;   // tokens
constexpr int Cc = 1024;   // channels
constexpr int Kk = 16;     // sparse K
constexpr int HK = 256;    // heads*keys
constexpr int KSPL = 8;    // K1 k-split factor
constexpr unsigned NBLK = 512;

__device__ inline __bf16 f2bf(float f) {
    union { __hip_bfloat16 h; __bf16 b; } u;
    u.h = __float2bfloat16(f);
    return u.b;
}

// Async global->LDS, 16B/lane; LDS dest = wave-uniform base + lane*16 (m104).
__device__ inline void load_lds16(const void* g, void* l) {
    auto gp = (const __attribute__((address_space(1))) unsigned int*)(uintptr_t)g;
    auto lp = (__attribute__((address_space(3))) unsigned int*)(uintptr_t)l;
    __builtin_amdgcn_global_load_lds(gp, lp, 16, 0, 0);
}

// 8 consecutive fp32 (global) -> bf16x8.
__device__ inline bf16x8 cvt8(const float* p) {
    f32x4 lo = *reinterpret_cast<const f32x4*>(p);
    f32x4 hi = *reinterpret_cast<const f32x4*>(p + 4);
    bf16x8 r;
    r[0] = f2bf(lo[0]); r[1] = f2bf(lo[1]); r[2] = f2bf(lo[2]); r[3] = f2bf(lo[3]);
    r[4] = f2bf(hi[0]); r[5] = f2bf(hi[1]); r[6] = f2bf(hi[2]); r[7] = f2bf(hi[3]);
    return r;
}

// Software grid barrier (graph-capture-safe; R17 -- cooperative launch is not
// capturable, R16's absmax==max|ref| showed the kernel never ran).
// Thread 0: device-scope ACQ_REL arrival (releases this block's prior writes),
// then ACQUIRE spin until all NBLK arrive (invalidates caches for later reads).
// Counter is memset to 0 on the stream before every launch (graph replays it).
// Spin bound turns any deadlock into a visible wrong answer, not a timeout.
__device__ inline void grid_sync(unsigned* cnt) {
    __syncthreads();
    if (threadIdx.x == 0) {
        __hip_atomic_fetch_add(cnt, 1u, __ATOMIC_ACQ_REL, __HIP_MEMORY_SCOPE_AGENT);
        unsigned spins = 0;
        while (__hip_atomic_load(cnt, __ATOMIC_ACQUIRE, __HIP_MEMORY_SCOPE_AGENT) < NBLK
               && ++spins < (1u << 30)) {
            __builtin_amdgcn_s_sleep(2);
        }
    }
    __syncthreads();
}

// R17: all four stages fused into ONE regular kernel, 512 blocks x 256 threads
// (2 blocks/CU co-resident by __launch_bounds__(256,2): 8 waves/CU needed, LDS
// 24KB/block allows 6/CU). Software grid_sync between phases. Phase math is
// byte-identical to the R15-verified 4-kernel version; only block remapping.
__global__ __launch_bounds__(256, 2)
void fused_all(const float* __restrict__ x,
               const float* __restrict__ W_attn,
               const float* __restrict__ W_proj,
               float* __restrict__ kv_part,       // [8][64][2048]
               __hip_bfloat16* __restrict__ QKb,  // [Bb][256][1024]
               __hip_bfloat16* __restrict__ vPt,  // [Bb][1024][256]
               __hip_bfloat16* __restrict__ w_ws, // [Bb][1024][256]
               __hip_bfloat16* __restrict__ xb,   // [Bb][1024][1024] bf16
               float* __restrict__ out,
               unsigned* __restrict__ bar)        // 3 zeroed counters
{
    __shared__ __align__(16) char smem[24576];

    const int tid  = threadIdx.x;
    const int lane = tid & 63;
    const int wave = tid >> 6;
    const int blk  = blockIdx.x;

    // ---------------- Phase 1: kv partials (blk<256) / x->bf16 cvt (blk>=256)
    if (blk >= 256) {
        const int cb = blk - 256;                 // 0..255
        const size_t base = (size_t)cb * 16384;   // 4M elems / 256
#pragma unroll
        for (int i = 0; i < 8; ++i) {
            size_t off = base + (size_t)(i * 256 + tid) * 8;
            *reinterpret_cast<bf16x8*>(xb + off) = cvt8(x + off);
        }
    } else {
        const float* Wkv = W_attn + (size_t)Cc * Cc;
        __hip_bfloat16* As = (__hip_bfloat16*)smem;            // 64*40
        __hip_bfloat16* Bs = As + 64 * 40;                     // 64*40
        const int wm = wave >> 1, wn = wave & 1;
        const int tileN = (blk & 31) * 64;
        const int kz = blk >> 5;                               // 0..7
        const int r16 = lane & 15;
        const int kq  = (lane >> 4) * 8;
        const int sr = tid >> 2, sc = (tid & 3) * 8;
        const size_t arow = (size_t)(sr >> 4) * Tt + (sr & 15); // first 16 tokens/batch

        f32x4 acc[2][2] = {};
        for (int kk = kz * 128; kk < kz * 128 + 128; kk += 32) {
            *reinterpret_cast<bf16x8*>(As + sr * 40 + sc) = cvt8(x + arow * Cc + kk + sc);
            *reinterpret_cast<bf16x8*>(Bs + sr * 40 + sc) = cvt8(Wkv + (size_t)(tileN + sr) * Cc + kk + sc);
            __syncthreads();
            bf16x8 a[2], b[2];
#pragma unroll
            for (int i = 0; i < 2; ++i) {
                a[i] = *reinterpret_cast<const bf16x8*>(As + (wm * 32 + i * 16 + r16) * 40 + kq);
                b[i] = *reinterpret_cast<const bf16x8*>(Bs + (wn * 32 + i * 16 + r16) * 40 + kq);
            }
#pragma unroll
            for (int i = 0; i < 2; ++i)
#pragma unroll
                for (int j = 0; j < 2; ++j)
                    acc[i][j] = __builtin_amdgcn_mfma_f32_16x16x32_bf16(a[i], b[j], acc[i][j], 0, 0, 0);
            __syncthreads();
        }

        const int crow0 = (lane >> 4) * 4;
        const int ccol  = lane & 15;
        float* outp = kv_part + (size_t)kz * 64 * 2048;
#pragma unroll
        for (int i = 0; i < 2; ++i)
#pragma unroll
            for (int j = 0; j < 2; ++j)
#pragma unroll
                for (int r = 0; r < 4; ++r)
                    outp[(size_t)(wm * 32 + i * 16 + crow0 + r) * 2048
                         + tileN + wn * 32 + j * 16 + ccol] = acc[i][j][r];
    }

    grid_sync(bar + 0);

    // ---------------- Phase 2: QK / vPt precompute (sel = sum of 8 partials)
    {
        float (*sel)[16] = (float (*)[16])smem;   // [64][16]
        const int type = blk >> 8;
        const int bh = (blk >> 2) & 63;
        const int cchunk = blk & 3;
        const int b = bh >> 4, h = bh & 15;

        for (int e = tid; e < Kk * 64; e += 256) {
            int k = e >> 6, d = e & 63;
            size_t off = (size_t)(b * Kk + k) * 2048 + type * 1024 + h * 64 + d;
            float s = 0.f;
#pragma unroll
            for (int p = 0; p < KSPL; ++p) s += kv_part[off + (size_t)p * 64 * 2048];
            sel[d][k] = s;
        }
        __syncthreads();

        const int c = cchunk * 256 + tid;
        float acc[Kk] = {};

        if (type == 0) {
            const float* wp = W_attn + (size_t)(h * 64) * 1024 + c;
#pragma unroll 8
            for (int d = 0; d < 64; ++d) {
                float wv = wp[(size_t)d * 1024];
                const float4* sv = reinterpret_cast<const float4*>(sel[d]);
                float4 s0 = sv[0], s1 = sv[1], s2 = sv[2], s3 = sv[3];
                acc[0]  += wv * s0.x; acc[1]  += wv * s0.y; acc[2]  += wv * s0.z; acc[3]  += wv * s0.w;
                acc[4]  += wv * s1.x; acc[5]  += wv * s1.y; acc[6]  += wv * s1.z; acc[7]  += wv * s1.w;
                acc[8]  += wv * s2.x; acc[9]  += wv * s2.y; acc[10] += wv * s2.z; acc[11] += wv * s2.w;
                acc[12] += wv * s3.x; acc[13] += wv * s3.y; acc[14] += wv * s3.z; acc[15] += wv * s3.w;
            }
#pragma unroll
            for (int k = 0; k < Kk; ++k)
                QKb[((size_t)b * HK + h * 16 + k) * 1024 + c] = __float2bfloat16(acc[k]);
        } else {
            const float* wrow = W_proj + (size_t)c * 1024 + h * 64;
#pragma unroll 8
            for (int d4 = 0; d4 < 64; d4 += 4) {
                float4 wv = *reinterpret_cast<const float4*>(wrow + d4);
                const float w4[4] = {wv.x, wv.y, wv.z, wv.w};
#pragma unroll
                for (int dd = 0; dd < 4; ++dd) {
                    float wvv = w4[dd];
                    const float4* sv = reinterpret_cast<const float4*>(sel[d4 + dd]);
                    float4 s0 = sv[0], s1 = sv[1], s2 = sv[2], s3 = sv[3];
                    acc[0]  += wvv * s0.x; acc[1]  += wvv * s0.y; acc[2]  += wvv * s0.z; acc[3]  += wvv * s0.w;
                    acc[4]  += wvv * s1.x; acc[5]  += wvv * s1.y; acc[6]  += wvv * s1.z; acc[7]  += wvv * s1.w;
                    acc[8]  += wvv * s2.x; acc[9]  += wvv * s2.y; acc[10] += wvv * s2.z; acc[11] += wvv * s2.w;
                    acc[12] += wvv * s3.x; acc[13] += wvv * s3.y; acc[14] += wvv * s3.z; acc[15] += wvv * s3.w;
                }
            }
            bf16x8 p0, p1;
#pragma unroll
            for (int k = 0; k < 8; ++k) { p0[k] = f2bf(acc[k]); p1[k] = f2bf(acc[k + 8]); }
            __hip_bfloat16* dst = vPt + ((size_t)b * 1024 + c) * HK + h * 16;
            *reinterpret_cast<bf16x8*>(dst) = p0;
            *reinterpret_cast<bf16x8*>(dst + 8) = p1;
        }
    }

    grid_sync(bar + 1);

    // ---------------- Phase 3: logits + fused masked softmax
    {
        __hip_bfloat16* Ah = (__hip_bfloat16*)smem;   // [4][32*32]
        __hip_bfloat16* Bh = Ah + 4 * 32 * 32;        // [4][64*32]
        const int bz = blk >> 7;                      // batch 0..3
        const int by = (blk >> 2) & 31;               // 0..31
        const int bx = blk & 3;                       // 0..3
        const __hip_bfloat16* A = xb + (size_t)bz * Tt * Cc;
        const __hip_bfloat16* Bm = QKb + (size_t)bz * HK * Cc;
        const int wm = wave >> 1, wn = wave & 1;
        const int tileM = by * 32;
        const int tileN = bx * 64;
        const int r16 = lane & 15;
        const int kq  = (lane >> 4) * 8;

        f32x4 acc[2] = {};
        for (int kk = 0; kk < Cc; kk += 128) {
            {
                int g = wave * 64 + lane;
#pragma unroll
                for (int s = 0; s < 4; ++s)
                    load_lds16(Bm + (size_t)(tileN + (g >> 2)) * Cc + kk + s * 32 + (g & 3) * 8,
                               Bh + s * 2048 + wave * 512);
#pragma unroll
                for (int h = 0; h < 2; ++h)
                    load_lds16(A + (size_t)(tileM + h * 16 + (lane >> 2)) * Cc + kk + wave * 32 + (lane & 3) * 8,
                               Ah + wave * 1024 + h * 512);
            }
            __syncthreads();

#pragma unroll
            for (int s = 0; s < 4; ++s) {
                bf16x8 a = *reinterpret_cast<const bf16x8*>(Ah + s * 1024 + (wm * 16 + r16) * 32 + kq);
#pragma unroll
                for (int j = 0; j < 2; ++j) {
                    bf16x8 b = *reinterpret_cast<const bf16x8*>(
                        Bh + s * 2048 + (wn * 32 + j * 16 + r16) * 32 + kq);
                    acc[j] = __builtin_amdgcn_mfma_f32_16x16x32_bf16(a, b, acc[j], 0, 0, 0);
                }
            }
            __syncthreads();
        }

        const int crow0 = (lane >> 4) * 4;
        const int ccol  = lane & 15;        // k index within the head
#pragma unroll
        for (int r = 0; r < 4; ++r) {
            int t = tileM + wm * 16 + crow0 + r;
            bool valid = (ccol <= t);
#pragma unroll
            for (int j = 0; j < 2; ++j) {
                int hk = tileN + wn * 32 + j * 16 + ccol;
                float v = acc[j][r] * 0.125f;
                float vm = valid ? v : -3.0e38f;
#pragma unroll
                for (int m = 1; m < 16; m <<= 1) vm = fmaxf(vm, __shfl_xor(vm, m));
                float e = valid ? __expf(v - vm) : 0.f;
                float s = e;
#pragma unroll
                for (int m = 1; m < 16; m <<= 1) s += __shfl_xor(s, m);
                w_ws[((size_t)bz * Tt + t) * HK + hk] = __float2bfloat16(e / s);
            }
        }
    }

    grid_sync(bar + 2);

    // ---------------- Phase 4: out = w @ vPt^T, 2 sequential 64x64 tiles/block
    {
        __hip_bfloat16* As = (__hip_bfloat16*)smem;   // [2][64*32]
        __hip_bfloat16* Bs = As + 2 * 64 * 32;        // [2][64*32]
        const int wm = wave >> 1, wn = wave & 1;
        const int r16 = lane & 15;
        const int kq  = (lane >> 4) * 8;

        for (int rep = 0; rep < 2; ++rep) {
            const int t = blk * 2 + rep;
            const int bz = t >> 8;
            const int by = (t >> 4) & 15;
            const int bx = t & 15;
            const __hip_bfloat16* A = w_ws + (size_t)bz * Tt * HK;
            const __hip_bfloat16* Bm = vPt + (size_t)bz * Cc * HK;
            const int tileM = by * 64;
            const int tileN = bx * 64;

            f32x4 acc[2][2] = {};
            for (int kk = 0; kk < HK; kk += 64) {
                {
                    int g = wave * 64 + lane;      // row g>>2, col (g&3)*8
#pragma unroll
                    for (int s = 0; s < 2; ++s) {
                        load_lds16(A + (size_t)(tileM + (g >> 2)) * HK + kk + s * 32 + (g & 3) * 8,
                                   As + s * 2048 + wave * 512);
                        load_lds16(Bm + (size_t)(tileN + (g >> 2)) * HK + kk + s * 32 + (g & 3) * 8,
                                   Bs + s * 2048 + wave * 512);
                    }
                }
                __syncthreads();
#pragma unroll
                for (int s = 0; s < 2; ++s) {
                    bf16x8 a[2], b[2];
#pragma unroll
                    for (int i = 0; i < 2; ++i) {
                        a[i] = *reinterpret_cast<const bf16x8*>(As + s * 2048 + (wm * 32 + i * 16 + r16) * 32 + kq);
                        b[i] = *reinterpret_cast<const bf16x8*>(Bs + s * 2048 + (wn * 32 + i * 16 + r16) * 32 + kq);
                    }
#pragma unroll
                    for (int i = 0; i < 2; ++i)
#pragma unroll
                        for (int j = 0; j < 2; ++j)
                            acc[i][j] = __builtin_amdgcn_mfma_f32_16x16x32_bf16(a[i], b[j], acc[i][j], 0, 0, 0);
                }
                __syncthreads();
            }

            const int crow0 = (lane >> 4) * 4;
            const int ccol  = lane & 15;
            float* outp = out + (size_t)bz * Tt * Cc;
#pragma unroll
            for (int i = 0; i < 2; ++i)
#pragma unroll
                for (int j = 0; j < 2; ++j)
#pragma unroll
                    for (int r = 0; r < 4; ++r)
                        outp[(size_t)(tileM + wm * 32 + i * 16 + crow0 + r) * Cc
                             + tileN + wn * 32 + j * 16 + ccol] = acc[i][j][r];
        }
    }
}

extern "C" void kernel_launch(void* const* d_in, const int* in_sizes, int n_in,
                              void* d_out, int out_size, void* d_ws, size_t ws_size,
                              hipStream_t stream)
{
    (void)in_sizes; (void)n_in; (void)out_size; (void)ws_size;
    const float* x      = (const float*)d_in[0];
    const float* W_attn = (const float*)d_in[1];
    const float* W_proj = (const float*)d_in[2];
    // d_in[3] = W_rel dead (round-4 verified): top_k values discarded; only
    // finite score at col 0 -> idx = [0..15] for every (h,t).
    float* out = (float*)d_out;

    char* ws = (char*)d_ws;
    float*          kv_part = (float*)ws;                        // 4 MB [8][64][2048]
    __hip_bfloat16* QKb  = (__hip_bfloat16*)(ws + (4u << 20));   // 2 MB [4][256][1024]
    __hip_bfloat16* vPt  = (__hip_bfloat16*)(ws + (6u << 20));   // 2 MB [4][1024][256]
    __hip_bfloat16* w_ws = (__hip_bfloat16*)(ws + (8u << 20));   // 2 MB [4][1024][256]
    __hip_bfloat16* xb   = (__hip_bfloat16*)(ws + (10u << 20));  // 8 MB [4][1024][1024]
    unsigned*       bar  = (unsigned*)(ws + (18u << 20));        // 3 barrier counters

    // Zero barrier counters on the stream (capture-legal; replays with graph).
    hipMemsetAsync(bar, 0, 256, stream);
    fused_all<<<dim3(NBLK), 256, 0, stream>>>(x, W_attn, W_proj, kv_part,
                                              QKb, vPt, w_ws, xb, out, bar);
}

// Round 6
// 222.884 us; speedup vs baseline: 1.1341x; 1.1341x over previous
//
#include <hip/hip_runtime.h>
#include <hip/hip_bf16.h>
#include <stdint.h>

typedef __bf16 bf16x8 __attribute__((ext_vector_type(8)));
typedef float  f32x4  __attribute__((ext_vector_type(4)));

constexpr int Bb = 4;      // batch
constexpr int Tt = 1024;   // tokens
constexpr int Cc = 1024;   // channels
constexpr int Kk = 16;     // sparse K
constexpr int HK = 256;    // heads*keys
constexpr int KSPL = 8;    // K1 k-split factor
constexpr unsigned NBLK = 512;

__device__ inline __bf16 f2bf(float f) {
    union { __hip_bfloat16 h; __bf16 b; } u;
    u.h = __float2bfloat16(f);
    return u.b;
}

// Async global->LDS, 16B/lane; LDS dest = wave-uniform base + lane*16 (m104).
__device__ inline void load_lds16(const void* g, void* l) {
    auto gp = (const __attribute__((address_space(1))) unsigned int*)(uintptr_t)g;
    auto lp = (__attribute__((address_space(3))) unsigned int*)(uintptr_t)l;
    __builtin_amdgcn_global_load_lds(gp, lp, 16, 0, 0);
}

// 8 consecutive fp32 (global) -> bf16x8.
__device__ inline bf16x8 cvt8(const float* p) {
    f32x4 lo = *reinterpret_cast<const f32x4*>(p);
    f32x4 hi = *reinterpret_cast<const f32x4*>(p + 4);
    bf16x8 r;
    r[0] = f2bf(lo[0]); r[1] = f2bf(lo[1]); r[2] = f2bf(lo[2]); r[3] = f2bf(lo[3]);
    r[4] = f2bf(hi[0]); r[5] = f2bf(hi[1]); r[6] = f2bf(hi[2]); r[7] = f2bf(hi[3]);
    return r;
}

// Software grid barrier, R20 (= R18 pattern, compile-fixed).
// R17 polled with ACQUIRE@AGENT -> per-poll L1/L2 invalidation -> continuous
// cache flush (fused_all 171us, HBM 534 GB/s). Fix: RELEASE arrival (one L2
// wb per block), RELAXED poll + s_sleep (no cache ops), then ONE acquire
// LOAD after exit (R19: __hip_atomic_fence doesn't exist in these headers;
// a single acquire atomic load gives the same one-shot invalidate).
__device__ inline void grid_sync(unsigned* cnt) {
    __syncthreads();
    if (threadIdx.x == 0) {
        __hip_atomic_fetch_add(cnt, 1u, __ATOMIC_RELEASE, __HIP_MEMORY_SCOPE_AGENT);
        unsigned spins = 0;
        while (__hip_atomic_load(cnt, __ATOMIC_RELAXED, __HIP_MEMORY_SCOPE_AGENT) < NBLK
               && ++spins < (1u << 27)) {
            __builtin_amdgcn_s_sleep(8);
        }
        (void)__hip_atomic_load(cnt, __ATOMIC_ACQUIRE, __HIP_MEMORY_SCOPE_AGENT);
    }
    __syncthreads();
}

// All four stages fused into ONE regular kernel, 512 blocks x 256 threads
// (2 blocks/CU co-resident by __launch_bounds__(256,2), VGPR=56 measured).
// Software grid_sync between phases. Phase math byte-identical to the
// R15-verified 4-kernel version; only block remapping.
__global__ __launch_bounds__(256, 2)
void fused_all(const float* __restrict__ x,
               const float* __restrict__ W_attn,
               const float* __restrict__ W_proj,
               float* __restrict__ kv_part,       // [8][64][2048]
               __hip_bfloat16* __restrict__ QKb,  // [Bb][256][1024]
               __hip_bfloat16* __restrict__ vPt,  // [Bb][1024][256]
               __hip_bfloat16* __restrict__ w_ws, // [Bb][1024][256]
               __hip_bfloat16* __restrict__ xb,   // [Bb][1024][1024] bf16
               float* __restrict__ out,
               unsigned* __restrict__ bar)        // zeroed counters, 64B apart
{
    __shared__ __align__(16) char smem[24576];

    const int tid  = threadIdx.x;
    const int lane = tid & 63;
    const int wave = tid >> 6;
    const int blk  = blockIdx.x;

    // ---------------- Phase 1: kv partials (blk<256) / x->bf16 cvt (blk>=256)
    if (blk >= 256) {
        const int cb = blk - 256;                 // 0..255
        const size_t base = (size_t)cb * 16384;   // 4M elems / 256
#pragma unroll
        for (int i = 0; i < 8; ++i) {
            size_t off = base + (size_t)(i * 256 + tid) * 8;
            *reinterpret_cast<bf16x8*>(xb + off) = cvt8(x + off);
        }
    } else {
        const float* Wkv = W_attn + (size_t)Cc * Cc;
        __hip_bfloat16* As = (__hip_bfloat16*)smem;            // 64*40
        __hip_bfloat16* Bs = As + 64 * 40;                     // 64*40
        const int wm = wave >> 1, wn = wave & 1;
        const int tileN = (blk & 31) * 64;
        const int kz = blk >> 5;                               // 0..7
        const int r16 = lane & 15;
        const int kq  = (lane >> 4) * 8;
        const int sr = tid >> 2, sc = (tid & 3) * 8;
        const size_t arow = (size_t)(sr >> 4) * Tt + (sr & 15); // first 16 tokens/batch

        f32x4 acc[2][2] = {};
        for (int kk = kz * 128; kk < kz * 128 + 128; kk += 32) {
            *reinterpret_cast<bf16x8*>(As + sr * 40 + sc) = cvt8(x + arow * Cc + kk + sc);
            *reinterpret_cast<bf16x8*>(Bs + sr * 40 + sc) = cvt8(Wkv + (size_t)(tileN + sr) * Cc + kk + sc);
            __syncthreads();
            bf16x8 a[2], b[2];
#pragma unroll
            for (int i = 0; i < 2; ++i) {
                a[i] = *reinterpret_cast<const bf16x8*>(As + (wm * 32 + i * 16 + r16) * 40 + kq);
                b[i] = *reinterpret_cast<const bf16x8*>(Bs + (wn * 32 + i * 16 + r16) * 40 + kq);
            }
#pragma unroll
            for (int i = 0; i < 2; ++i)
#pragma unroll
                for (int j = 0; j < 2; ++j)
                    acc[i][j] = __builtin_amdgcn_mfma_f32_16x16x32_bf16(a[i], b[j], acc[i][j], 0, 0, 0);
            __syncthreads();
        }

        const int crow0 = (lane >> 4) * 4;
        const int ccol  = lane & 15;
        float* outp = kv_part + (size_t)kz * 64 * 2048;
#pragma unroll
        for (int i = 0; i < 2; ++i)
#pragma unroll
            for (int j = 0; j < 2; ++j)
#pragma unroll
                for (int r = 0; r < 4; ++r)
                    outp[(size_t)(wm * 32 + i * 16 + crow0 + r) * 2048
                         + tileN + wn * 32 + j * 16 + ccol] = acc[i][j][r];
    }

    grid_sync(bar + 0);

    // ---------------- Phase 2: QK / vPt precompute (sel = sum of 8 partials)
    {
        // Rows padded 16->20 floats (80B, float4-aligned): [64][16] put column
        // writes on 2 banks (1.69M conflicts in R17 PMC); stride-20 spreads
        // the 64-lane column write over 8+ banks. Reads are row broadcasts.
        float (*sel)[20] = (float (*)[20])smem;   // [64][20]
        const int type = blk >> 8;
        const int bh = (blk >> 2) & 63;
        const int cchunk = blk & 3;
        const int b = bh >> 4, h = bh & 15;

        for (int e = tid; e < Kk * 64; e += 256) {
            int k = e >> 6, d = e & 63;
            size_t off = (size_t)(b * Kk + k) * 2048 + type * 1024 + h * 64 + d;
            float s = 0.f;
#pragma unroll
            for (int p = 0; p < KSPL; ++p) s += kv_part[off + (size_t)p * 64 * 2048];
            sel[d][k] = s;
        }
        __syncthreads();

        const int c = cchunk * 256 + tid;
        float acc[Kk] = {};

        if (type == 0) {
            const float* wp = W_attn + (size_t)(h * 64) * 1024 + c;
#pragma unroll 8
            for (int d = 0; d < 64; ++d) {
                float wv = wp[(size_t)d * 1024];
                const float4* sv = reinterpret_cast<const float4*>(sel[d]);
                float4 s0 = sv[0], s1 = sv[1], s2 = sv[2], s3 = sv[3];
                acc[0]  += wv * s0.x; acc[1]  += wv * s0.y; acc[2]  += wv * s0.z; acc[3]  += wv * s0.w;
                acc[4]  += wv * s1.x; acc[5]  += wv * s1.y; acc[6]  += wv * s1.z; acc[7]  += wv * s1.w;
                acc[8]  += wv * s2.x; acc[9]  += wv * s2.y; acc[10] += wv * s2.z; acc[11] += wv * s2.w;
                acc[12] += wv * s3.x; acc[13] += wv * s3.y; acc[14] += wv * s3.z; acc[15] += wv * s3.w;
            }
#pragma unroll
            for (int k = 0; k < Kk; ++k)
                QKb[((size_t)b * HK + h * 16 + k) * 1024 + c] = __float2bfloat16(acc[k]);
        } else {
            const float* wrow = W_proj + (size_t)c * 1024 + h * 64;
#pragma unroll 8
            for (int d4 = 0; d4 < 64; d4 += 4) {
                float4 wv = *reinterpret_cast<const float4*>(wrow + d4);
                const float w4[4] = {wv.x, wv.y, wv.z, wv.w};
#pragma unroll
                for (int dd = 0; dd < 4; ++dd) {
                    float wvv = w4[dd];
                    const float4* sv = reinterpret_cast<const float4*>(sel[d4 + dd]);
                    float4 s0 = sv[0], s1 = sv[1], s2 = sv[2], s3 = sv[3];
                    acc[0]  += wvv * s0.x; acc[1]  += wvv * s0.y; acc[2]  += wvv * s0.z; acc[3]  += wvv * s0.w;
                    acc[4]  += wvv * s1.x; acc[5]  += wvv * s1.y; acc[6]  += wvv * s1.z; acc[7]  += wvv * s1.w;
                    acc[8]  += wvv * s2.x; acc[9]  += wvv * s2.y; acc[10] += wvv * s2.z; acc[11] += wvv * s2.w;
                    acc[12] += wvv * s3.x; acc[13] += wvv * s3.y; acc[14] += wvv * s3.z; acc[15] += wvv * s3.w;
                }
            }
            bf16x8 p0, p1;
#pragma unroll
            for (int k = 0; k < 8; ++k) { p0[k] = f2bf(acc[k]); p1[k] = f2bf(acc[k + 8]); }
            __hip_bfloat16* dst = vPt + ((size_t)b * 1024 + c) * HK + h * 16;
            *reinterpret_cast<bf16x8*>(dst) = p0;
            *reinterpret_cast<bf16x8*>(dst + 8) = p1;
        }
    }

    grid_sync(bar + 16);

    // ---------------- Phase 3: logits + fused masked softmax
    {
        __hip_bfloat16* Ah = (__hip_bfloat16*)smem;   // [4][32*32]
        __hip_bfloat16* Bh = Ah + 4 * 32 * 32;        // [4][64*32]
        const int bz = blk >> 7;                      // batch 0..3
        const int by = (blk >> 2) & 31;               // 0..31
        const int bx = blk & 3;                       // 0..3
        const __hip_bfloat16* A = xb + (size_t)bz * Tt * Cc;
        const __hip_bfloat16* Bm = QKb + (size_t)bz * HK * Cc;
        const int wm = wave >> 1, wn = wave & 1;
        const int tileM = by * 32;
        const int tileN = bx * 64;
        const int r16 = lane & 15;
        const int kq  = (lane >> 4) * 8;

        f32x4 acc[2] = {};
        for (int kk = 0; kk < Cc; kk += 128) {
            {
                int g = wave * 64 + lane;
#pragma unroll
                for (int s = 0; s < 4; ++s)
                    load_lds16(Bm + (size_t)(tileN + (g >> 2)) * Cc + kk + s * 32 + (g & 3) * 8,
                               Bh + s * 2048 + wave * 512);
#pragma unroll
                for (int h = 0; h < 2; ++h)
                    load_lds16(A + (size_t)(tileM + h * 16 + (lane >> 2)) * Cc + kk + wave * 32 + (lane & 3) * 8,
                               Ah + wave * 1024 + h * 512);
            }
            __syncthreads();

#pragma unroll
            for (int s = 0; s < 4; ++s) {
                bf16x8 a = *reinterpret_cast<const bf16x8*>(Ah + s * 1024 + (wm * 16 + r16) * 32 + kq);
#pragma unroll
                for (int j = 0; j < 2; ++j) {
                    bf16x8 b = *reinterpret_cast<const bf16x8*>(
                        Bh + s * 2048 + (wn * 32 + j * 16 + r16) * 32 + kq);
                    acc[j] = __builtin_amdgcn_mfma_f32_16x16x32_bf16(a, b, acc[j], 0, 0, 0);
                }
            }
            __syncthreads();
        }

        const int crow0 = (lane >> 4) * 4;
        const int ccol  = lane & 15;        // k index within the head
#pragma unroll
        for (int r = 0; r < 4; ++r) {
            int t = tileM + wm * 16 + crow0 + r;
            bool valid = (ccol <= t);
#pragma unroll
            for (int j = 0; j < 2; ++j) {
                int hk = tileN + wn * 32 + j * 16 + ccol;
                float v = acc[j][r] * 0.125f;
                float vm = valid ? v : -3.0e38f;
#pragma unroll
                for (int m = 1; m < 16; m <<= 1) vm = fmaxf(vm, __shfl_xor(vm, m));
                float e = valid ? __expf(v - vm) : 0.f;
                float s = e;
#pragma unroll
                for (int m = 1; m < 16; m <<= 1) s += __shfl_xor(s, m);
                w_ws[((size_t)bz * Tt + t) * HK + hk] = __float2bfloat16(e / s);
            }
        }
    }

    grid_sync(bar + 32);

    // ---------------- Phase 4: out = w @ vPt^T, 2 sequential 64x64 tiles/block
    {
        __hip_bfloat16* As = (__hip_bfloat16*)smem;   // [2][64*32]
        __hip_bfloat16* Bs = As + 2 * 64 * 32;        // [2][64*32]
        const int wm = wave >> 1, wn = wave & 1;
        const int r16 = lane & 15;
        const int kq  = (lane >> 4) * 8;

        for (int rep = 0; rep < 2; ++rep) {
            const int t = blk * 2 + rep;
            const int bz = t >> 8;
            const int by = (t >> 4) & 15;
            const int bx = t & 15;
            const __hip_bfloat16* A = w_ws + (size_t)bz * Tt * HK;
            const __hip_bfloat16* Bm = vPt + (size_t)bz * Cc * HK;
            const int tileM = by * 64;
            const int tileN = bx * 64;

            f32x4 acc[2][2] = {};
            for (int kk = 0; kk < HK; kk += 64) {
                {
                    int g = wave * 64 + lane;      // row g>>2, col (g&3)*8
#pragma unroll
                    for (int s = 0; s < 2; ++s) {
                        load_lds16(A + (size_t)(tileM + (g >> 2)) * HK + kk + s * 32 + (g & 3) * 8,
                                   As + s * 2048 + wave * 512);
                        load_lds16(Bm + (size_t)(tileN + (g >> 2)) * HK + kk + s * 32 + (g & 3) * 8,
                                   Bs + s * 2048 + wave * 512);
                    }
                }
                __syncthreads();
#pragma unroll
                for (int s = 0; s < 2; ++s) {
                    bf16x8 a[2], b[2];
#pragma unroll
                    for (int i = 0; i < 2; ++i) {
                        a[i] = *reinterpret_cast<const bf16x8*>(As + s * 2048 + (wm * 32 + i * 16 + r16) * 32 + kq);
                        b[i] = *reinterpret_cast<const bf16x8*>(Bs + s * 2048 + (wn * 32 + i * 16 + r16) * 32 + kq);
                    }
#pragma unroll
                    for (int i = 0; i < 2; ++i)
#pragma unroll
                        for (int j = 0; j < 2; ++j)
                            acc[i][j] = __builtin_amdgcn_mfma_f32_16x16x32_bf16(a[i], b[j], acc[i][j], 0, 0, 0);
                }
                __syncthreads();
            }

            const int crow0 = (lane >> 4) * 4;
            const int ccol  = lane & 15;
            float* outp = out + (size_t)bz * Tt * Cc;
#pragma unroll
            for (int i = 0; i < 2; ++i)
#pragma unroll
                for (int j = 0; j < 2; ++j)
#pragma unroll
                    for (int r = 0; r < 4; ++r)
                        outp[(size_t)(tileM + wm * 32 + i * 16 + crow0 + r) * Cc
                             + tileN + wn * 32 + j * 16 + ccol] = acc[i][j][r];
        }
    }
}

extern "C" void kernel_launch(void* const* d_in, const int* in_sizes, int n_in,
                              void* d_out, int out_size, void* d_ws, size_t ws_size,
                              hipStream_t stream)
{
    (void)in_sizes; (void)n_in; (void)out_size; (void)ws_size;
    const float* x      = (const float*)d_in[0];
    const float* W_attn = (const float*)d_in[1];
    const float* W_proj = (const float*)d_in[2];
    // d_in[3] = W_rel dead (round-4 verified): top_k values discarded; only
    // finite score at col 0 -> idx = [0..15] for every (h,t).
    float* out = (float*)d_out;

    char* ws = (char*)d_ws;
    float*          kv_part = (float*)ws;                        // 4 MB [8][64][2048]
    __hip_bfloat16* QKb  = (__hip_bfloat16*)(ws + (4u << 20));   // 2 MB [4][256][1024]
    __hip_bfloat16* vPt  = (__hip_bfloat16*)(ws + (6u << 20));   // 2 MB [4][1024][256]
    __hip_bfloat16* w_ws = (__hip_bfloat16*)(ws + (8u << 20));   // 2 MB [4][1024][256]
    __hip_bfloat16* xb   = (__hip_bfloat16*)(ws + (10u << 20));  // 8 MB [4][1024][1024]
    unsigned*       bar  = (unsigned*)(ws + (18u << 20));        // counters, 64B apart

    // Zero barrier counters on the stream (capture-legal; replays with graph).
    (void)hipMemsetAsync(bar, 0, 256, stream);
    fused_all<<<dim3(NBLK), 256, 0, stream>>>(x, W_attn, W_proj, kv_part,
                                              QKb, vPt, w_ws, xb, out, bar);
}

// Round 7
// 113.356 us; speedup vs baseline: 2.2299x; 1.9662x over previous
//
#include <hip/hip_runtime.h>
#include <hip/hip_bf16.h>
#include <stdint.h>

typedef __bf16 bf16x8 __attribute__((ext_vector_type(8)));
typedef float  f32x4  __attribute__((ext_vector_type(4)));

constexpr int Bb = 4;      // batch
constexpr int Tt = 1024;   // tokens
constexpr int Cc = 1024;   // channels
constexpr int Kk = 16;     // sparse K
constexpr int HK = 256;    // heads*keys
constexpr int KSPL = 8;    // K1 k-split factor

__device__ inline __bf16 f2bf(float f) {
    union { __hip_bfloat16 h; __bf16 b; } u;
    u.h = __float2bfloat16(f);
    return u.b;
}

// Async global->LDS, 16B/lane; LDS dest = wave-uniform base + lane*16 (m104).
__device__ inline void load_lds16(const void* g, void* l) {
    auto gp = (const __attribute__((address_space(1))) unsigned int*)(uintptr_t)g;
    auto lp = (__attribute__((address_space(3))) unsigned int*)(uintptr_t)l;
    __builtin_amdgcn_global_load_lds(gp, lp, 16, 0, 0);
}

// 8 consecutive fp32 (global) -> bf16x8.
__device__ inline bf16x8 cvt8(const float* p) {
    f32x4 lo = *reinterpret_cast<const f32x4*>(p);
    f32x4 hi = *reinterpret_cast<const f32x4*>(p + 4);
    bf16x8 r;
    r[0] = f2bf(lo[0]); r[1] = f2bf(lo[1]); r[2] = f2bf(lo[2]); r[3] = f2bf(lo[3]);
    r[4] = f2bf(hi[0]); r[5] = f2bf(hi[1]); r[6] = f2bf(hi[2]); r[7] = f2bf(hi[3]);
    return r;
}

// R21 NOTE: single-kernel fusion is REFUTED on this platform. R16: cooperative
// launch not graph-capturable (silent no-op). R17/R20: software grid barrier
// costs ~40us/sync at 512 blocks regardless of barrier flavor (RELAXED poll +
// one-shot acquire identical FETCH_SIZE to per-poll-acquire; kernel 155-171us,
// all pipes idle). Launch boundaries under graph replay (~4us) are CHEAPER
// than any in-kernel grid sync here. Keep the 4-kernel pipeline.

// K1: kv partials + x->bf16 conversion.
// z = 0..7:  kv_part[kz][64][2048] = x_sel[64x128k] @ Wkv^T[2048x128k] (k-split x8).
// z = 8..15: 256 blocks grid-stride convert x (16.8 MB fp32) -> xb (8.4 MB bf16).
__global__ __launch_bounds__(256)
void kv_gemm(const float* __restrict__ x, const float* __restrict__ Wkv,
             float* __restrict__ kv_part, __hip_bfloat16* __restrict__ xb)
{
    __shared__ __hip_bfloat16 As[64 * 40];
    __shared__ __hip_bfloat16 Bs[64 * 40];
    const int tid = threadIdx.x;

    if (blockIdx.z >= KSPL) {
        // x -> bf16 cvt: 256 blocks x 256 threads x 64 elems (8 iters of 8).
        const int cb = (blockIdx.z - KSPL) * 32 + blockIdx.x;   // 0..255
        const size_t base = (size_t)cb * 16384;                 // 4M elems / 256
#pragma unroll
        for (int i = 0; i < 8; ++i) {
            size_t off = base + (size_t)(i * 256 + tid) * 8;
            *reinterpret_cast<bf16x8*>(xb + off) = cvt8(x + off);
        }
        return;
    }

    const int lane = tid & 63;
    const int wave = tid >> 6;
    const int wm = wave >> 1, wn = wave & 1;
    const int tileN = blockIdx.x * 64;
    const int kz = blockIdx.z;
    const int r16 = lane & 15;
    const int kq  = (lane >> 4) * 8;

    const int sr = tid >> 2, sc = (tid & 3) * 8;
    const size_t arow = (size_t)(sr >> 4) * Tt + (sr & 15);   // gather: first 16 tokens/batch

    f32x4 acc[2][2] = {};
    for (int kk = kz * 128; kk < kz * 128 + 128; kk += 32) {
        *reinterpret_cast<bf16x8*>(As + sr * 40 + sc) = cvt8(x + arow * Cc + kk + sc);
        *reinterpret_cast<bf16x8*>(Bs + sr * 40 + sc) = cvt8(Wkv + (size_t)(tileN + sr) * Cc + kk + sc);
        __syncthreads();
        bf16x8 a[2], b[2];
#pragma unroll
        for (int i = 0; i < 2; ++i) {
            a[i] = *reinterpret_cast<const bf16x8*>(As + (wm * 32 + i * 16 + r16) * 40 + kq);
            b[i] = *reinterpret_cast<const bf16x8*>(Bs + (wn * 32 + i * 16 + r16) * 40 + kq);
        }
#pragma unroll
        for (int i = 0; i < 2; ++i)
#pragma unroll
            for (int j = 0; j < 2; ++j)
                acc[i][j] = __builtin_amdgcn_mfma_f32_16x16x32_bf16(a[i], b[j], acc[i][j], 0, 0, 0);
        __syncthreads();
    }

    const int crow0 = (lane >> 4) * 4;
    const int ccol  = lane & 15;
    float* outp = kv_part + (size_t)kz * 64 * 2048;
#pragma unroll
    for (int i = 0; i < 2; ++i)
#pragma unroll
        for (int j = 0; j < 2; ++j)
#pragma unroll
            for (int r = 0; r < 4; ++r)
                outp[(size_t)(wm * 32 + i * 16 + crow0 + r) * 2048
                     + tileN + wn * 32 + j * 16 + ccol] = acc[i][j][r];
}

// K2: QK / vPt precompute; sel = sum of 8 kv partials. Grid 512. Unroll 8.
// R21: sel rows padded 16->20 floats (80B, float4-aligned). The [64][16]
// layout made the column write sel[d][k] a 32-way bank conflict (stride 64B
// -> 64 lanes on 2 banks; ~1.5M conflicts in R17/R20 PMC); stride-20 spreads
// over 8 banks. Reads are row broadcasts (conflict-free either way).
__global__ __launch_bounds__(256)
void precompute(const float* __restrict__ kv_part,  // [8][64][2048]
                const float* __restrict__ W_attn,   // rows 0..1023 = Wq
                const float* __restrict__ W_proj,
                __hip_bfloat16* __restrict__ QKb,   // [Bb][256][1024]
                __hip_bfloat16* __restrict__ vPt)   // [Bb][1024][256]
{
    __shared__ float sel[64][20];   // [d][k] padded
    const int blk = blockIdx.x;
    const int type = blk >> 8;
    const int bh = (blk >> 2) & 63;
    const int cchunk = blk & 3;
    const int b = bh >> 4, h = bh & 15;
    const int tid = threadIdx.x;

    for (int e = tid; e < Kk * 64; e += 256) {
        int k = e >> 6, d = e & 63;
        size_t off = (size_t)(b * Kk + k) * 2048 + type * 1024 + h * 64 + d;
        float s = 0.f;
#pragma unroll
        for (int p = 0; p < KSPL; ++p) s += kv_part[off + (size_t)p * 64 * 2048];
        sel[d][k] = s;
    }
    __syncthreads();

    const int c = cchunk * 256 + tid;
    float acc[Kk] = {};

    if (type == 0) {
        const float* wp = W_attn + (size_t)(h * 64) * 1024 + c;
#pragma unroll 8
        for (int d = 0; d < 64; ++d) {
            float wv = wp[(size_t)d * 1024];
            const float4* sv = reinterpret_cast<const float4*>(sel[d]);
            float4 s0 = sv[0], s1 = sv[1], s2 = sv[2], s3 = sv[3];
            acc[0]  += wv * s0.x; acc[1]  += wv * s0.y; acc[2]  += wv * s0.z; acc[3]  += wv * s0.w;
            acc[4]  += wv * s1.x; acc[5]  += wv * s1.y; acc[6]  += wv * s1.z; acc[7]  += wv * s1.w;
            acc[8]  += wv * s2.x; acc[9]  += wv * s2.y; acc[10] += wv * s2.z; acc[11] += wv * s2.w;
            acc[12] += wv * s3.x; acc[13] += wv * s3.y; acc[14] += wv * s3.z; acc[15] += wv * s3.w;
        }
#pragma unroll
        for (int k = 0; k < Kk; ++k)
            QKb[((size_t)b * HK + h * 16 + k) * 1024 + c] = __float2bfloat16(acc[k]);
    } else {
        const float* wrow = W_proj + (size_t)c * 1024 + h * 64;
#pragma unroll 8
        for (int d4 = 0; d4 < 64; d4 += 4) {
            float4 wv = *reinterpret_cast<const float4*>(wrow + d4);
            const float w4[4] = {wv.x, wv.y, wv.z, wv.w};
#pragma unroll
            for (int dd = 0; dd < 4; ++dd) {
                float wvv = w4[dd];
                const float4* sv = reinterpret_cast<const float4*>(sel[d4 + dd]);
                float4 s0 = sv[0], s1 = sv[1], s2 = sv[2], s3 = sv[3];
                acc[0]  += wvv * s0.x; acc[1]  += wvv * s0.y; acc[2]  += wvv * s0.z; acc[3]  += wvv * s0.w;
                acc[4]  += wvv * s1.x; acc[5]  += wvv * s1.y; acc[6]  += wvv * s1.z; acc[7]  += wvv * s1.w;
                acc[8]  += wvv * s2.x; acc[9]  += wvv * s2.y; acc[10] += wvv * s2.z; acc[11] += wvv * s2.w;
                acc[12] += wvv * s3.x; acc[13] += wvv * s3.y; acc[14] += wvv * s3.z; acc[15] += wvv * s3.w;
            }
        }
        bf16x8 p0, p1;
#pragma unroll
        for (int k = 0; k < 8; ++k) { p0[k] = f2bf(acc[k]); p1[k] = f2bf(acc[k + 8]); }
        __hip_bfloat16* dst = vPt + ((size_t)b * 1024 + c) * HK + h * 16;
        *reinterpret_cast<bf16x8*>(dst) = p0;
        *reinterpret_cast<bf16x8*>(dst + 8) = p1;
    }
}

// K3: logits + fused masked softmax. A-tile staged via global_load_lds
// directly from pre-converted bf16 xb -- no per-iter cvt VALU, no ds_writes.
// A layout = stride-32 sub-blocks (2-way bank alias = free), same as B.
// BK=128, grid (4,32,4) = 512 blocks (2/CU).
__global__ __launch_bounds__(256)
void logits_softmax(const __hip_bfloat16* __restrict__ xb,
                    const __hip_bfloat16* __restrict__ QKb,
                    __hip_bfloat16* __restrict__ wout)
{
    __shared__ __hip_bfloat16 Ah[4][32 * 32];
    __shared__ __hip_bfloat16 Bh[4][64 * 32];

    const __hip_bfloat16* A = xb + (size_t)blockIdx.z * Tt * Cc;
    const __hip_bfloat16* Bm = QKb + (size_t)blockIdx.z * HK * Cc;

    const int tid = threadIdx.x;
    const int lane = tid & 63;
    const int wave = tid >> 6;
    const int wm = wave >> 1, wn = wave & 1;
    const int tileM = blockIdx.y * 32;
    const int tileN = blockIdx.x * 64;
    const int r16 = lane & 15;
    const int kq  = (lane >> 4) * 8;

    f32x4 acc[2] = {};
    for (int kk = 0; kk < Cc; kk += 128) {
        {
            int g = wave * 64 + lane;
            // B: each wave stages one 64x32 row-slice per sub-block.
#pragma unroll
            for (int s = 0; s < 4; ++s)
                load_lds16(Bm + (size_t)(tileN + (g >> 2)) * Cc + kk + s * 32 + (g & 3) * 8,
                           &Bh[s][0] + wave * 512);
            // A: wave w owns sub-block w (32 cols), 2 half-tiles of 16 rows.
#pragma unroll
            for (int h = 0; h < 2; ++h)
                load_lds16(A + (size_t)(tileM + h * 16 + (lane >> 2)) * Cc + kk + wave * 32 + (lane & 3) * 8,
                           &Ah[wave][0] + h * 512);
        }
        __syncthreads();

#pragma unroll
        for (int s = 0; s < 4; ++s) {
            bf16x8 a = *reinterpret_cast<const bf16x8*>(&Ah[s][0] + (wm * 16 + r16) * 32 + kq);
#pragma unroll
            for (int j = 0; j < 2; ++j) {
                bf16x8 b = *reinterpret_cast<const bf16x8*>(
                    &Bh[s][0] + (wn * 32 + j * 16 + r16) * 32 + kq);
                acc[j] = __builtin_amdgcn_mfma_f32_16x16x32_bf16(a, b, acc[j], 0, 0, 0);
            }
        }
        __syncthreads();
    }

    const int crow0 = (lane >> 4) * 4;
    const int ccol  = lane & 15;        // k index within the head
#pragma unroll
    for (int r = 0; r < 4; ++r) {
        int t = tileM + wm * 16 + crow0 + r;
        bool valid = (ccol <= t);
#pragma unroll
        for (int j = 0; j < 2; ++j) {
            int hk = tileN + wn * 32 + j * 16 + ccol;
            float v = acc[j][r] * 0.125f;
            float vm = valid ? v : -3.0e38f;
#pragma unroll
            for (int m = 1; m < 16; m <<= 1) vm = fmaxf(vm, __shfl_xor(vm, m));
            float e = valid ? __expf(v - vm) : 0.f;
            float s = e;
#pragma unroll
            for (int m = 1; m < 16; m <<= 1) s += __shfl_xor(s, m);
            wout[((size_t)blockIdx.z * Tt + t) * HK + hk] = __float2bfloat16(e / s);
        }
    }
}

// K4: out[b] = w[b] @ vPt[b]^T (M=1024, N=1024, K=256), bf16 in, fp32 out.
// BK=64 (4 iterations), 8 MFMA/wave per barrier pair. Sub-block LDS
// As[2][64x32] / Bs[2][64x32], conflict-free stride-32 rows.
// 64x64 tiles -> grid (16,16,4) = 1024 blocks = 4/CU.
__global__ __launch_bounds__(256)
void out_gemm(const __hip_bfloat16* __restrict__ Aw,
              const __hip_bfloat16* __restrict__ Bv,
              float* __restrict__ Cout)
{
    __shared__ __hip_bfloat16 As[2][64 * 32];
    __shared__ __hip_bfloat16 Bs[2][64 * 32];

    const __hip_bfloat16* A = Aw + (size_t)blockIdx.z * Tt * HK;
    const __hip_bfloat16* Bm = Bv + (size_t)blockIdx.z * Cc * HK;

    const int lane = threadIdx.x & 63;
    const int wave = threadIdx.x >> 6;
    const int wm = wave >> 1, wn = wave & 1;
    const int tileM = blockIdx.y * 64;
    const int tileN = blockIdx.x * 64;
    const int r16 = lane & 15;
    const int kq  = (lane >> 4) * 8;

    f32x4 acc[2][2] = {};
    for (int kk = 0; kk < HK; kk += 64) {
        {
            int g = wave * 64 + lane;      // row g>>2, col (g&3)*8 within sub-block
#pragma unroll
            for (int s = 0; s < 2; ++s) {
                load_lds16(A + (size_t)(tileM + (g >> 2)) * HK + kk + s * 32 + (g & 3) * 8,
                           &As[s][0] + wave * 512);
                load_lds16(Bm + (size_t)(tileN + (g >> 2)) * HK + kk + s * 32 + (g & 3) * 8,
                           &Bs[s][0] + wave * 512);
            }
        }
        __syncthreads();
#pragma unroll
        for (int s = 0; s < 2; ++s) {
            bf16x8 a[2], b[2];
#pragma unroll
            for (int i = 0; i < 2; ++i) {
                a[i] = *reinterpret_cast<const bf16x8*>(&As[s][0] + (wm * 32 + i * 16 + r16) * 32 + kq);
                b[i] = *reinterpret_cast<const bf16x8*>(&Bs[s][0] + (wn * 32 + i * 16 + r16) * 32 + kq);
            }
#pragma unroll
            for (int i = 0; i < 2; ++i)
#pragma unroll
                for (int j = 0; j < 2; ++j)
                    acc[i][j] = __builtin_amdgcn_mfma_f32_16x16x32_bf16(a[i], b[j], acc[i][j], 0, 0, 0);
        }
        __syncthreads();
    }

    const int crow0 = (lane >> 4) * 4;
    const int ccol  = lane & 15;
    float* outp = Cout + (size_t)blockIdx.z * Tt * Cc;
#pragma unroll
    for (int i = 0; i < 2; ++i)
#pragma unroll
        for (int j = 0; j < 2; ++j)
#pragma unroll
            for (int r = 0; r < 4; ++r)
                outp[(size_t)(tileM + wm * 32 + i * 16 + crow0 + r) * Cc
                     + tileN + wn * 32 + j * 16 + ccol] = acc[i][j][r];
}

extern "C" void kernel_launch(void* const* d_in, const int* in_sizes, int n_in,
                              void* d_out, int out_size, void* d_ws, size_t ws_size,
                              hipStream_t stream)
{
    (void)in_sizes; (void)n_in; (void)out_size; (void)ws_size;
    const float* x      = (const float*)d_in[0];
    const float* W_attn = (const float*)d_in[1];
    const float* W_proj = (const float*)d_in[2];
    // d_in[3] = W_rel dead (round-4 verified): top_k values discarded; only
    // finite score at col 0 -> idx = [0..15] for every (h,t).
    float* out = (float*)d_out;

    char* ws = (char*)d_ws;
    float*          kv_part = (float*)ws;                        // 4 MB [8][64][2048]
    __hip_bfloat16* QKb  = (__hip_bfloat16*)(ws + (4u << 20));   // 2 MB [4][256][1024]
    __hip_bfloat16* vPt  = (__hip_bfloat16*)(ws + (6u << 20));   // 2 MB [4][1024][256]
    __hip_bfloat16* w_ws = (__hip_bfloat16*)(ws + (8u << 20));   // 2 MB [4][1024][256]
    __hip_bfloat16* xb   = (__hip_bfloat16*)(ws + (10u << 20));  // 8 MB [4][1024][1024]

    // K1: kv partials (z<8) + x->bf16 cvt (z>=8). 512 blocks total.
    kv_gemm<<<dim3(32, 1, 2 * KSPL), 256, 0, stream>>>(x, W_attn + (size_t)Cc * Cc, kv_part, xb);
    // K2: QK / vPt precompute (sums 8 kv partials; fp32 math, bf16 out).
    precompute<<<512, 256, 0, stream>>>(kv_part, W_attn, W_proj, QKb, vPt);
    // K3: logits GEMM + fused masked softmax -> w. A from xb via global_load_lds.
    logits_softmax<<<dim3(HK / 64, Tt / 32, Bb), 256, 0, stream>>>(xb, QKb, w_ws);
    // K4: out = w @ vPt^T -> d_out fp32. 1024 blocks (4/CU), BK=64.
    out_gemm<<<dim3(16, 16, Bb), 256, 0, stream>>>(w_ws, vPt, out);
}